// Round 3
// baseline (365.084 us; speedup 1.0000x reference)
//
#include <hip/hip_runtime.h>

constexpr int NN = 50000;    // nodes
constexpr int NE = 1600000;  // edges
constexpr int NG = 128;      // graphs
constexpr int BSTRIDE = 96;  // adj bucket slots per node (deg~Poisson(32), max~58)

// R11 fill rewrite: two-phase bucketing replaces the 8 redundant dst-range
// passes (R10 post-mortem: fill was wave-throughput-bound, 200K waves x
// ~233cy retire; 8x redundant dst reads = 50MB HBM). Phase A reads each edge
// ONCE, packs (dst<<16)|src into a uint32, scatters into 8 dst-range buckets
// via LDS-aggregated cursors (coalesced writes). Phase B keeps the proven
// XCD-local atomic+store pattern (pass = blockIdx&7) but with 1.6M threads
// total instead of 12.8M.
constexpr int FILL_RANGES = 8;
constexpr int NODES_PER_PASS = 6250;              // 8*6250 = 50000
constexpr int BUCKET_CAP = 204800;                // mean 200K, +11 sigma
constexpr int FILLB_BLOCKS_PER_RANGE = BUCKET_CAP / 256;  // 800

// agg1 fusion geometry: 36 nodes/block, 7 lanes/node = 252 active threads
constexpr int A1_NODES = 36;
constexpr int A1_BLOCKS = (NN + A1_NODES - 1) / A1_NODES;  // 1389

// workspace layout (bytes)
#define OFF_CNT      0            // int[50000] atomic cursor; == deg after fill
#define OFF_GSUM     200000       // float[128*20]
#define OFF_GCNT     210240       // float[128]
#define OFF_BCUR     210752       // int[8] bucket cursors
#define ZERO_BYTES   210784
#define OFF_ADJ      210816       // ushort[50000*96] = 9.6MB bucketed adjacency
#define OFF_X1F      9810816      // fp8[50000*128] rows 128B-aligned (6.4MB)
#define OFF_X2B      16210816     // bf16[50000*32] rows 64B (3.2MB)
#define OFF_BUCKET   19410816     // uint32[8*204800] = 6.55MB packed edges
// end: 25964416 (~26MB)

typedef float v2f __attribute__((ext_vector_type(2)));

// ---- bf16 helpers ---------------------------------------------------------
__device__ __forceinline__ unsigned short f2bf(float x) {      // RNE
    unsigned int v = __float_as_uint(x);
    return (unsigned short)((v + 0x7FFFu + ((v >> 16) & 1u)) >> 16);
}
__device__ __forceinline__ float bflo(unsigned int u) { return __uint_as_float(u << 16); }
__device__ __forceinline__ float bfhi(unsigned int u) { return __uint_as_float(u & 0xFFFF0000u); }

// ---- phase A: bucket scatter ---------------------------------------------
// Each edge read once; packed (dst<<16)|src (both < 2^16). Per-block LDS
// counts -> one global atomicAdd per range per block -> coalesced writes
// into the block's contiguous reservation within each bucket.
__global__ __launch_bounds__(256) void k_bucket(const int* __restrict__ src,
                                                const int* __restrict__ dst,
                                                int* __restrict__ bcur,
                                                unsigned int* __restrict__ bucket) {
    __shared__ int lcnt[FILL_RANGES];
    __shared__ int lbase[FILL_RANGES];
    const int t = threadIdx.x;
    if (t < FILL_RANGES) lcnt[t] = 0;
    __syncthreads();
    const int i = blockIdx.x * 256 + t;
    const int d = dst[i];
    const int s = src[i];
    const int r = (unsigned)d / (unsigned)NODES_PER_PASS;
    const int lp = atomicAdd(&lcnt[r], 1);
    __syncthreads();
    if (t < FILL_RANGES) {
        lbase[t] = (lcnt[t] > 0) ? atomicAdd(&bcur[t], lcnt[t]) : 0;
    }
    __syncthreads();
    bucket[r * BUCKET_CAP + lbase[r] + lp] =
        ((unsigned int)d << 16) | (unsigned int)s;
}

// ---- phase B: XCD-local adj fill -----------------------------------------
// Range r handled only by blocks with blockIdx&7==r (round-robin XCD
// dispatch): cnt slice (25KB) + adj slice (1.2MB) stay L2-local on one XCD,
// so atomic-returns and 2B stores never ping-pong across L2s.
__global__ __launch_bounds__(256) void k_fill2(const unsigned int* __restrict__ bucket,
                                               const int* __restrict__ bcur,
                                               int* __restrict__ cnt,
                                               unsigned short* __restrict__ adj) {
    const int r = blockIdx.x & 7;
    const int chunk = blockIdx.x >> 3;
    const int t = chunk * 256 + threadIdx.x;
    if (t >= bcur[r]) return;
    const unsigned int e = bucket[r * BUCKET_CAP + t];
    const int d = (int)(e >> 16);
    const int s = (int)(e & 0xFFFFu);
    const int p = atomicAdd(&cnt[d], 1);
    if (p < BSTRIDE) adj[d * BSTRIDE + p] = (unsigned short)s;
}

// ---- X1f = fp8_e4m3(feat @ W1)  (50000x128 @ 128x100), row = 128 fp8 -----
// Register-tiled: thread = 4 nodes x 4 cols; the 4 cols pack into one uint.
__global__ __launch_bounds__(256) void k_gemm1(const float4* __restrict__ feat4,
                                               const float* __restrict__ W1,
                                               unsigned int* __restrict__ X1f) {
    const int t = threadIdx.x;
    if (t >= 250) return;
    const int cg = t % 25;            // cols [4cg, 4cg+4)
    const int nq = t / 25;            // node quad within block
    const int node0 = blockIdx.x * 40 + nq * 4;
    const int col0 = cg * 4;

    float acc[4][4];
#pragma unroll
    for (int i = 0; i < 4; ++i)
#pragma unroll
        for (int j = 0; j < 4; ++j) acc[i][j] = 0.f;

    for (int k4 = 0; k4 < 32; ++k4) {
        float4 f[4];
#pragma unroll
        for (int i = 0; i < 4; ++i) f[i] = feat4[(node0 + i) * 32 + k4];
        float4 wr[4];
#pragma unroll
        for (int kk = 0; kk < 4; ++kk)
            wr[kk] = *(const float4*)(W1 + (k4 * 4 + kk) * 100 + col0);
#pragma unroll
        for (int kk = 0; kk < 4; ++kk) {
#pragma unroll
            for (int i = 0; i < 4; ++i) {
                const float fv = (kk == 0) ? f[i].x
                               : (kk == 1) ? f[i].y
                               : (kk == 2) ? f[i].z : f[i].w;
                acc[i][0] += fv * wr[kk].x;
                acc[i][1] += fv * wr[kk].y;
                acc[i][2] += fv * wr[kk].z;
                acc[i][3] += fv * wr[kk].w;
            }
        }
    }
#pragma unroll
    for (int i = 0; i < 4; ++i) {
        int u = 0;
        u = __builtin_amdgcn_cvt_pk_fp8_f32(acc[i][0], acc[i][1], u, false);
        u = __builtin_amdgcn_cvt_pk_fp8_f32(acc[i][2], acc[i][3], u, true);
        X1f[(node0 + i) * 32 + cg] = (unsigned int)u;
        if (cg == 24) {  // zero pad cols 100..127 (uints 25..31)
#pragma unroll
            for (int z = 25; z < 32; ++z) X1f[(node0 + i) * 32 + z] = 0u;
        }
    }
}

// ---- fused layer-1 aggregate + gemm2 --------------------------------------
// Phase 1 (7 lanes/node, 36 nodes/block): h = relu(where(deg>0, mean(fp8row),
// fp8row) + b1) -> LDS. Phase 2: X2b = bf16(h @ W2) per block from LDS.
// Serial edge loop (R3/R5: unroll regresses).
__global__ __launch_bounds__(256) void k_agg1g2(
        const uint4* __restrict__ X1u, const int* __restrict__ cnt,
        const unsigned short* __restrict__ adj, const float* __restrict__ b1,
        const float* __restrict__ W2, unsigned int* __restrict__ X2b) {
    __shared__ float hl[A1_NODES * 100];   // 14.4KB relu'd layer-1 rows
    __shared__ float w2s[100 * 20];        // 8KB
    const int t = threadIdx.x;
    const int node0 = blockIdx.x * A1_NODES;
    for (int i = t; i < 2000; i += 256) w2s[i] = W2[i];

    if (t < A1_NODES * 7) {
        const int nl = t / 7;
        const int q = t - nl * 7;            // cols [16q, 16q+16)
        const int node = node0 + nl;
        if (node < NN) {
            const int d = cnt[node];
            const unsigned short* ab = adj + node * BSTRIDE;
            float a[16];
#pragma unroll
            for (int j = 0; j < 16; ++j) a[j] = 0.f;

#define ACC4(UU, B) { v2f l_ = __builtin_amdgcn_cvt_pk_f32_fp8((int)(UU), false); \
                      v2f h_ = __builtin_amdgcn_cvt_pk_f32_fp8((int)(UU), true);  \
                      a[B+0] += l_.x; a[B+1] += l_.y; a[B+2] += h_.x; a[B+3] += h_.y; }
#define SET4(UU, B) { v2f l_ = __builtin_amdgcn_cvt_pk_f32_fp8((int)(UU), false); \
                      v2f h_ = __builtin_amdgcn_cvt_pk_f32_fp8((int)(UU), true);  \
                      a[B+0] = l_.x; a[B+1] = l_.y; a[B+2] = h_.x; a[B+3] = h_.y; }

            for (int i = 0; i < d; ++i) {
                const int s = (int)ab[i];           // broadcast in 7-lane group
                const uint4 u = X1u[s * 8 + q];     // 16B of 128B row (1 line/edge)
                ACC4(u.x, 0) ACC4(u.y, 4) ACC4(u.z, 8) ACC4(u.w, 12)
            }
            if (d > 0) {
                const float inv = 1.f / (float)d;
#pragma unroll
                for (int j = 0; j < 16; ++j) a[j] *= inv;
            } else {
                const uint4 u = X1u[node * 8 + q];
                SET4(u.x, 0) SET4(u.y, 4) SET4(u.z, 8) SET4(u.w, 12)
            }
#undef ACC4
#undef SET4
            const int col0 = 16 * q;
            float* hrow = hl + nl * 100 + col0;
            const int nc = (q < 6) ? 16 : 4;       // q==6: cols 96..99 only
#pragma unroll 4
            for (int j = 0; j < nc; ++j)
                hrow[j] = fmaxf(a[j] + b1[col0 + j], 0.f);
        }
    }
    __syncthreads();

    // phase 2: per (node, slot) slot<16; slot<10 -> bf16 pair, else zero pad
    for (int idx = t; idx < A1_NODES * 16; idx += 256) {
        const int nl = idx >> 4;
        const int node = node0 + nl;
        if (node >= NN) break;
        const int j = idx & 15;
        unsigned int o = 0u;
        if (j < 10) {
            const float* h = hl + nl * 100;
            float a0 = 0.f, a1 = 0.f;
#pragma unroll 5
            for (int k = 0; k < 100; ++k) {
                const float hv = h[k];
                a0 += hv * w2s[k * 20 + 2 * j];
                a1 += hv * w2s[k * 20 + 2 * j + 1];
            }
            o = (unsigned int)f2bf(a0) | ((unsigned int)f2bf(a1) << 16);
        }
        X2b[node * 16 + j] = o;
    }
}

// ---- layer-2 aggregate + LDS per-graph reduce -----------------------------
__global__ __launch_bounds__(320) void k_agg2(const uint2* __restrict__ X2v,
                                              const int* __restrict__ cnt,
                                              const unsigned short* __restrict__ adj,
                                              const float* __restrict__ b2,
                                              const int* __restrict__ graph_id,
                                              float* __restrict__ g_sum,
                                              float* __restrict__ g_cnt) {
    __shared__ float lsum[NG * 20];
    __shared__ float lcnt[NG];
    const int t = threadIdx.x;
    for (int i = t; i < NG * 20; i += 320) lsum[i] = 0.f;
    for (int i = t; i < NG; i += 320) lcnt[i] = 0.f;
    __syncthreads();

    const int node = blockIdx.x * 64 + t / 5;
    const int q = t % 5;                      // cols [4q, 4q+4)
    if (node < NN) {
        const int d = cnt[node];
        const unsigned short* ab = adj + node * BSTRIDE;
        float ax = 0.f, ay = 0.f, az = 0.f, aw = 0.f;
        for (int i = 0; i < d; ++i) {
            const int s = (int)ab[i];
            const uint2 u = X2v[s * 8 + q];   // 8B of the 64B bf16 row
            ax += bflo(u.x); ay += bfhi(u.x);
            az += bflo(u.y); aw += bfhi(u.y);
        }
        if (d > 0) {
            const float inv = 1.f / (float)d;
            ax *= inv; ay *= inv; az *= inv; aw *= inv;
        } else {
            const uint2 u = X2v[node * 8 + q];
            ax = bflo(u.x); ay = bfhi(u.x);
            az = bflo(u.y); aw = bfhi(u.y);
        }
        const int col0 = 4 * q;
        const float hx = fmaxf(ax + b2[col0 + 0], 0.f);
        const float hy = fmaxf(ay + b2[col0 + 1], 0.f);
        const float hz = fmaxf(az + b2[col0 + 2], 0.f);
        const float hw = fmaxf(aw + b2[col0 + 3], 0.f);
        const int g = graph_id[node];
        atomicAdd(&lsum[g * 20 + col0 + 0], hx);
        atomicAdd(&lsum[g * 20 + col0 + 1], hy);
        atomicAdd(&lsum[g * 20 + col0 + 2], hz);
        atomicAdd(&lsum[g * 20 + col0 + 3], hw);
        if (q == 0) atomicAdd(&lcnt[g], 1.f);
    }
    __syncthreads();

    const int first = blockIdx.x * 64;
    const int last = min(first + 63, NN - 1);
    const int gmin = graph_id[first];
    const int span = graph_id[last] - gmin + 1;
    for (int idx = t; idx < span * 20; idx += 320) {
        const int g = gmin + idx / 20;
        const int c = idx - (idx / 20) * 20;
        const float v = lsum[g * 20 + c];
        if (v != 0.f) atomicAdd(&g_sum[g * 20 + c], v);
    }
    for (int idx = t; idx < span; idx += 320) {
        const float v = lcnt[gmin + idx];
        if (v != 0.f) atomicAdd(&g_cnt[gmin + idx], v);
    }
}

// ---- final: hg = g_sum/max(cnt,1); out = relu([hg,self]@Wf1+bf1)@Wf2+bf2 --
__global__ __launch_bounds__(128) void k_final(const float* __restrict__ g_sum,
                                               const float* __restrict__ g_cnt,
                                               const float* __restrict__ self_feat,
                                               const float* __restrict__ Wf1,
                                               const float* __restrict__ bf1,
                                               const float* __restrict__ Wf2,
                                               const float* __restrict__ bf2,
                                               float* __restrict__ out) {
    const int g = threadIdx.x;  // 128 graphs, one block
    float fused[36];
    const float cnt = fmaxf(g_cnt[g], 1.f);
    const float inv = 1.f / cnt;
#pragma unroll
    for (int j = 0; j < 20; ++j) fused[j] = g_sum[g * 20 + j] * inv;
#pragma unroll
    for (int j = 0; j < 16; ++j) fused[20 + j] = self_feat[g * 16 + j];
    float o = bf2[0];
#pragma unroll
    for (int i = 0; i < 10; ++i) {
        float t = bf1[i];
#pragma unroll
        for (int k = 0; k < 36; ++k) t += fused[k] * Wf1[k * 10 + i];
        o += fmaxf(t, 0.f) * Wf2[i];
    }
    out[g] = o;
}

extern "C" void kernel_launch(void* const* d_in, const int* in_sizes, int n_in,
                              void* d_out, int out_size, void* d_ws, size_t ws_size,
                              hipStream_t stream) {
    const float* feat      = (const float*)d_in[0];
    const float* self_feat = (const float*)d_in[1];
    const int*   src       = (const int*)d_in[2];
    const int*   dst       = (const int*)d_in[3];
    const int*   graph_id  = (const int*)d_in[4];
    const float* W1        = (const float*)d_in[5];
    const float* b1        = (const float*)d_in[6];
    const float* W2        = (const float*)d_in[7];
    const float* b2        = (const float*)d_in[8];
    const float* Wf1       = (const float*)d_in[9];
    const float* bf1       = (const float*)d_in[10];
    const float* Wf2       = (const float*)d_in[11];
    const float* bf2       = (const float*)d_in[12];

    char* w = (char*)d_ws;
    int*            cnt      = (int*)(w + OFF_CNT);
    float*          g_sum    = (float*)(w + OFF_GSUM);
    float*          g_cnt    = (float*)(w + OFF_GCNT);
    int*            bcur     = (int*)(w + OFF_BCUR);
    unsigned short* adj      = (unsigned short*)(w + OFF_ADJ);
    unsigned int*   X1f      = (unsigned int*)(w + OFF_X1F);
    unsigned int*   X2b      = (unsigned int*)(w + OFF_X2B);
    unsigned int*   bucket   = (unsigned int*)(w + OFF_BUCKET);

    hipMemsetAsync(w, 0, ZERO_BYTES, stream);  // cnt + g_sum + g_cnt + bcur

    k_bucket<<<NE / 256, 256, 0, stream>>>(src, dst, bcur, bucket);
    k_fill2<<<FILL_RANGES * FILLB_BLOCKS_PER_RANGE, 256, 0, stream>>>(
        bucket, bcur, cnt, adj);
    k_gemm1<<<1250, 256, 0, stream>>>((const float4*)feat, W1, X1f);
    k_agg1g2<<<A1_BLOCKS, 256, 0, stream>>>((const uint4*)X1f, cnt, adj, b1,
                                            W2, X2b);
    k_agg2<<<(NN + 63) / 64, 320, 0, stream>>>((const uint2*)X2b, cnt,
                                               adj, b2, graph_id, g_sum, g_cnt);
    k_final<<<1, 128, 0, stream>>>(g_sum, g_cnt, self_feat, Wf1, bf1, Wf2, bf2,
                                   (float*)d_out);
}

// Round 4
// 296.017 us; speedup vs baseline: 1.2333x; 1.2333x over previous
//
#include <hip/hip_runtime.h>

constexpr int NN = 50000;    // nodes
constexpr int NE = 1600000;  // edges
constexpr int NG = 128;      // graphs
constexpr int BSTRIDE = 96;  // adj bucket slots per node (deg~Poisson(32), max~58)

// Fill: R2-champion form restored. R11 lesson: ANY design doing the 1.6M
// atomicAdd-with-return + scattered 2B stores lands at ~70us (k_fill2 did it
// with coalesced pre-bucketed input: still 69us). The 8-pass redundant reads
// are nearly free (overlap the atomic stalls). Single-line global cursors
// (R11 k_bucket) are fatal: 6250 serialized line handoffs = 75us alone.
constexpr int FILL_PASSES = 8;
constexpr int NODES_PER_PASS = 6250;              // 8*6250 = 50000
constexpr int BLOCKS_PER_PASS = (NE + 255) / 256; // 6250

// R12: agg kernels are the hidden ~190us. Theory: serial deg~32 dependent-
// gather chain per node with only 7 (agg1) / 5 (agg2) live lanes per node.
// Split edge list across 2 lane-halves (16 lanes/node, wave-aligned) ->
// half the chain, 2.3x live lanes, same traffic; merge via shfl_xor(8).
constexpr int A1_NODES = 16;                       // nodes per agg1g2 block
constexpr int A1_BLOCKS = NN / A1_NODES;           // 3125 (exact)
constexpr int A2_BLOCKS = NN / 16;                 // 3125 (exact)

// workspace layout (bytes)
#define OFF_CNT      0            // int[50000] atomic cursor; == deg after fill
#define OFF_GSUM     200000       // float[128*20]
#define OFF_GCNT     210240       // float[128]
#define ZERO_BYTES   210752
#define OFF_ADJ      210752       // ushort[50000*96] = 9.6MB bucketed adjacency
#define OFF_X1F      9810816      // fp8[50000*128] rows 128B-aligned (6.4MB)
#define OFF_X2B      16210816     // bf16[50000*32] rows 64B (3.2MB)
// end: 19410816 (~19MB)

typedef float v2f __attribute__((ext_vector_type(2)));

// ---- bf16 helpers ---------------------------------------------------------
__device__ __forceinline__ unsigned short f2bf(float x) {      // RNE
    unsigned int v = __float_as_uint(x);
    return (unsigned short)((v + 0x7FFFu + ((v >> 16) & 1u)) >> 16);
}
__device__ __forceinline__ float bflo(unsigned int u) { return __uint_as_float(u << 16); }
__device__ __forceinline__ float bfhi(unsigned int u) { return __uint_as_float(u & 0xFFFF0000u); }

// ---- bucketed fill, XCD-aware dst-range passes (R0/R2 champion form) ------
__global__ void k_fill(const int* __restrict__ src, const int* __restrict__ dst,
                       int* __restrict__ cnt, unsigned short* __restrict__ adj) {
    const int pass = blockIdx.x & 7;          // XCD-aligned (round-robin dispatch)
    const int chunk = blockIdx.x >> 3;
    const int i = chunk * 256 + threadIdx.x;
    if (i >= NE) return;
    const int d = dst[i];
    const int lo = pass * NODES_PER_PASS;
    if (d >= lo && d < lo + NODES_PER_PASS) {
        const int p = atomicAdd(&cnt[d], 1);
        if (p < BSTRIDE) adj[d * BSTRIDE + p] = (unsigned short)src[i];
    }
}

// ---- X1f = fp8_e4m3(feat @ W1)  (50000x128 @ 128x100), row = 128 fp8 -----
// Register-tiled: thread = 4 nodes x 4 cols; the 4 cols pack into one uint.
__global__ __launch_bounds__(256) void k_gemm1(const float4* __restrict__ feat4,
                                               const float* __restrict__ W1,
                                               unsigned int* __restrict__ X1f) {
    const int t = threadIdx.x;
    if (t >= 250) return;
    const int cg = t % 25;            // cols [4cg, 4cg+4)
    const int nq = t / 25;            // node quad within block
    const int node0 = blockIdx.x * 40 + nq * 4;
    const int col0 = cg * 4;

    float acc[4][4];
#pragma unroll
    for (int i = 0; i < 4; ++i)
#pragma unroll
        for (int j = 0; j < 4; ++j) acc[i][j] = 0.f;

    for (int k4 = 0; k4 < 32; ++k4) {
        float4 f[4];
#pragma unroll
        for (int i = 0; i < 4; ++i) f[i] = feat4[(node0 + i) * 32 + k4];
        float4 wr[4];
#pragma unroll
        for (int kk = 0; kk < 4; ++kk)
            wr[kk] = *(const float4*)(W1 + (k4 * 4 + kk) * 100 + col0);
#pragma unroll
        for (int kk = 0; kk < 4; ++kk) {
#pragma unroll
            for (int i = 0; i < 4; ++i) {
                const float fv = (kk == 0) ? f[i].x
                               : (kk == 1) ? f[i].y
                               : (kk == 2) ? f[i].z : f[i].w;
                acc[i][0] += fv * wr[kk].x;
                acc[i][1] += fv * wr[kk].y;
                acc[i][2] += fv * wr[kk].z;
                acc[i][3] += fv * wr[kk].w;
            }
        }
    }
#pragma unroll
    for (int i = 0; i < 4; ++i) {
        int u = 0;
        u = __builtin_amdgcn_cvt_pk_fp8_f32(acc[i][0], acc[i][1], u, false);
        u = __builtin_amdgcn_cvt_pk_fp8_f32(acc[i][2], acc[i][3], u, true);
        X1f[(node0 + i) * 32 + cg] = (unsigned int)u;
        if (cg == 24) {  // zero pad cols 100..127 (uints 25..31)
#pragma unroll
            for (int z = 25; z < 32; ++z) X1f[(node0 + i) * 32 + z] = 0u;
        }
    }
}

// ---- fused layer-1 aggregate + gemm2, 16 lanes/node ----------------------
// Lane layout per node: l = t&15, q = l&7 (16-col slice, q<7 active),
// half = l>>3 (edge-list half). Each half serially gathers its d/2 edges
// (one 128B row line per edge, split over 7x16B lane loads); halves merge
// via shfl_xor(8). Phase 2: X2b = bf16(h @ W2), exactly 1 slot/thread.
__global__ __launch_bounds__(256) void k_agg1g2(
        const uint4* __restrict__ X1u, const int* __restrict__ cnt,
        const unsigned short* __restrict__ adj, const float* __restrict__ b1,
        const float* __restrict__ W2, unsigned int* __restrict__ X2b) {
    __shared__ float hl[A1_NODES * 100];   // 6.4KB relu'd layer-1 rows
    __shared__ float w2s[100 * 20];        // 8KB
    const int t = threadIdx.x;
    const int node0 = blockIdx.x * A1_NODES;
    for (int i = t; i < 2000; i += 256) w2s[i] = W2[i];

    const int nl   = t >> 4;
    const int l    = t & 15;
    const int q    = l & 7;              // cols [16q,16q+16), active q<7
    const int half = l >> 3;
    const int node = node0 + nl;         // always < NN (3125*16 = 50000)
    const int d = cnt[node];
    const unsigned short* ab = adj + node * BSTRIDE;
    float a[16];
#pragma unroll
    for (int j = 0; j < 16; ++j) a[j] = 0.f;

#define ACC4(UU, B) { v2f l_ = __builtin_amdgcn_cvt_pk_f32_fp8((int)(UU), false); \
                      v2f h_ = __builtin_amdgcn_cvt_pk_f32_fp8((int)(UU), true);  \
                      a[B+0] += l_.x; a[B+1] += l_.y; a[B+2] += h_.x; a[B+3] += h_.y; }
#define SET4(UU, B) { v2f l_ = __builtin_amdgcn_cvt_pk_f32_fp8((int)(UU), false); \
                      v2f h_ = __builtin_amdgcn_cvt_pk_f32_fp8((int)(UU), true);  \
                      a[B+0] = l_.x; a[B+1] = l_.y; a[B+2] = h_.x; a[B+3] = h_.y; }

    if (q < 7) {
        if (d == 0) {
            if (half == 0) {             // keep prior feature; half 1 adds 0
                const uint4 u = X1u[node * 8 + q];
                SET4(u.x, 0) SET4(u.y, 4) SET4(u.z, 8) SET4(u.w, 12)
            }
        } else {
            const int i0 = half ? (d >> 1) : 0;
            const int i1 = half ? d : (d >> 1);
            for (int i = i0; i < i1; ++i) {
                const int s = (int)ab[i];        // broadcast in 8-lane half
                const uint4 u = X1u[s * 8 + q];  // 16B of 128B row
                ACC4(u.x, 0) ACC4(u.y, 4) ACC4(u.z, 8) ACC4(u.w, 12)
            }
        }
    }
#undef ACC4
#undef SET4
    // merge halves (all 256 threads participate; 16-lane groups wave-aligned)
#pragma unroll
    for (int j = 0; j < 16; ++j) a[j] += __shfl_xor(a[j], 8);

    if (half == 0 && q < 7) {
        if (d > 0) {
            const float inv = 1.f / (float)d;
#pragma unroll
            for (int j = 0; j < 16; ++j) a[j] *= inv;
        }
        const int col0 = 16 * q;
        float* hrow = hl + nl * 100 + col0;
        const int nc = (q < 6) ? 16 : 4;       // q==6: cols 96..99 only
#pragma unroll 4
        for (int j = 0; j < nc; ++j)
            hrow[j] = fmaxf(a[j] + b1[col0 + j], 0.f);
    }
    __syncthreads();

    // phase 2: thread = (node, slot); slot<10 -> bf16 pair, else zero pad
    const int j = t & 15;
    unsigned int o = 0u;
    if (j < 10) {
        const float* h = hl + nl * 100;
        float a0 = 0.f, a1 = 0.f;
#pragma unroll 5
        for (int k = 0; k < 100; ++k) {
            const float hv = h[k];
            a0 += hv * w2s[k * 20 + 2 * j];
            a1 += hv * w2s[k * 20 + 2 * j + 1];
        }
        o = (unsigned int)f2bf(a0) | ((unsigned int)f2bf(a1) << 16);
    }
    X2b[node * 16 + j] = o;
}

// ---- layer-2 aggregate + LDS per-graph reduce, 16 lanes/node --------------
// Same half-split as agg1g2: q = l&7 (uint2 col slice, q<5 active),
// half = l>>3; merge via shfl_xor(8).
__global__ __launch_bounds__(256) void k_agg2(const uint2* __restrict__ X2v,
                                              const int* __restrict__ cnt,
                                              const unsigned short* __restrict__ adj,
                                              const float* __restrict__ b2,
                                              const int* __restrict__ graph_id,
                                              float* __restrict__ g_sum,
                                              float* __restrict__ g_cnt) {
    __shared__ float lsum[NG * 20];
    __shared__ float lcnt[NG];
    const int t = threadIdx.x;
    for (int i = t; i < NG * 20; i += 256) lsum[i] = 0.f;
    if (t < NG) lcnt[t] = 0.f;
    __syncthreads();

    const int nl   = t >> 4;
    const int l    = t & 15;
    const int q    = l & 7;              // cols [4q,4q+4), active q<5
    const int half = l >> 3;
    const int node = blockIdx.x * 16 + nl;   // always < NN (3125*16 = 50000)
    const int d = cnt[node];
    const unsigned short* ab = adj + node * BSTRIDE;
    float ax = 0.f, ay = 0.f, az = 0.f, aw = 0.f;
    if (q < 5) {
        if (d == 0) {
            if (half == 0) {
                const uint2 u = X2v[node * 8 + q];
                ax = bflo(u.x); ay = bfhi(u.x);
                az = bflo(u.y); aw = bfhi(u.y);
            }
        } else {
            const int i0 = half ? (d >> 1) : 0;
            const int i1 = half ? d : (d >> 1);
            for (int i = i0; i < i1; ++i) {
                const int s = (int)ab[i];
                const uint2 u = X2v[s * 8 + q];   // 8B of the 64B bf16 row
                ax += bflo(u.x); ay += bfhi(u.x);
                az += bflo(u.y); aw += bfhi(u.y);
            }
        }
    }
    ax += __shfl_xor(ax, 8);
    ay += __shfl_xor(ay, 8);
    az += __shfl_xor(az, 8);
    aw += __shfl_xor(aw, 8);

    if (half == 0 && q < 5) {
        if (d > 0) {
            const float inv = 1.f / (float)d;
            ax *= inv; ay *= inv; az *= inv; aw *= inv;
        }
        const int col0 = 4 * q;
        const float hx = fmaxf(ax + b2[col0 + 0], 0.f);
        const float hy = fmaxf(ay + b2[col0 + 1], 0.f);
        const float hz = fmaxf(az + b2[col0 + 2], 0.f);
        const float hw = fmaxf(aw + b2[col0 + 3], 0.f);
        const int g = graph_id[node];
        atomicAdd(&lsum[g * 20 + col0 + 0], hx);
        atomicAdd(&lsum[g * 20 + col0 + 1], hy);
        atomicAdd(&lsum[g * 20 + col0 + 2], hz);
        atomicAdd(&lsum[g * 20 + col0 + 3], hw);
    }
    if (l == 0) atomicAdd(&lcnt[graph_id[node]], 1.f);
    __syncthreads();

    const int first = blockIdx.x * 16;
    const int gmin = graph_id[first];
    const int span = graph_id[first + 15] - gmin + 1;
    for (int idx = t; idx < span * 20; idx += 256) {
        const int g = gmin + idx / 20;
        const int c = idx - (idx / 20) * 20;
        const float v = lsum[g * 20 + c];
        if (v != 0.f) atomicAdd(&g_sum[g * 20 + c], v);
    }
    for (int idx = t; idx < span; idx += 256) {
        const float v = lcnt[gmin + idx];
        if (v != 0.f) atomicAdd(&g_cnt[gmin + idx], v);
    }
}

// ---- final: hg = g_sum/max(cnt,1); out = relu([hg,self]@Wf1+bf1)@Wf2+bf2 --
__global__ __launch_bounds__(128) void k_final(const float* __restrict__ g_sum,
                                               const float* __restrict__ g_cnt,
                                               const float* __restrict__ self_feat,
                                               const float* __restrict__ Wf1,
                                               const float* __restrict__ bf1,
                                               const float* __restrict__ Wf2,
                                               const float* __restrict__ bf2,
                                               float* __restrict__ out) {
    const int g = threadIdx.x;  // 128 graphs, one block
    float fused[36];
    const float cnt = fmaxf(g_cnt[g], 1.f);
    const float inv = 1.f / cnt;
#pragma unroll
    for (int j = 0; j < 20; ++j) fused[j] = g_sum[g * 20 + j] * inv;
#pragma unroll
    for (int j = 0; j < 16; ++j) fused[20 + j] = self_feat[g * 16 + j];
    float o = bf2[0];
#pragma unroll
    for (int i = 0; i < 10; ++i) {
        float t = bf1[i];
#pragma unroll
        for (int k = 0; k < 36; ++k) t += fused[k] * Wf1[k * 10 + i];
        o += fmaxf(t, 0.f) * Wf2[i];
    }
    out[g] = o;
}

extern "C" void kernel_launch(void* const* d_in, const int* in_sizes, int n_in,
                              void* d_out, int out_size, void* d_ws, size_t ws_size,
                              hipStream_t stream) {
    const float* feat      = (const float*)d_in[0];
    const float* self_feat = (const float*)d_in[1];
    const int*   src       = (const int*)d_in[2];
    const int*   dst       = (const int*)d_in[3];
    const int*   graph_id  = (const int*)d_in[4];
    const float* W1        = (const float*)d_in[5];
    const float* b1        = (const float*)d_in[6];
    const float* W2        = (const float*)d_in[7];
    const float* b2        = (const float*)d_in[8];
    const float* Wf1       = (const float*)d_in[9];
    const float* bf1       = (const float*)d_in[10];
    const float* Wf2       = (const float*)d_in[11];
    const float* bf2       = (const float*)d_in[12];

    char* w = (char*)d_ws;
    int*            cnt      = (int*)(w + OFF_CNT);
    float*          g_sum    = (float*)(w + OFF_GSUM);
    float*          g_cnt    = (float*)(w + OFF_GCNT);
    unsigned short* adj      = (unsigned short*)(w + OFF_ADJ);
    unsigned int*   X1f      = (unsigned int*)(w + OFF_X1F);
    unsigned int*   X2b      = (unsigned int*)(w + OFF_X2B);

    hipMemsetAsync(w, 0, ZERO_BYTES, stream);  // cnt + g_sum + g_cnt

    k_fill<<<FILL_PASSES * BLOCKS_PER_PASS, 256, 0, stream>>>(src, dst, cnt, adj);
    k_gemm1<<<1250, 256, 0, stream>>>((const float4*)feat, W1, X1f);
    k_agg1g2<<<A1_BLOCKS, 256, 0, stream>>>((const uint4*)X1f, cnt, adj, b1,
                                            W2, X2b);
    k_agg2<<<A2_BLOCKS, 256, 0, stream>>>((const uint2*)X2b, cnt,
                                          adj, b2, graph_id, g_sum, g_cnt);
    k_final<<<1, 128, 0, stream>>>(g_sum, g_cnt, self_feat, Wf1, bf1, Wf2, bf2,
                                   (float*)d_out);
}

// Round 5
// 270.414 us; speedup vs baseline: 1.3501x; 1.0947x over previous
//
#include <hip/hip_runtime.h>

constexpr int NN = 50000;    // nodes
constexpr int NE = 1600000;  // edges
constexpr int NG = 128;      // graphs
constexpr int BSTRIDE = 96;  // adj bucket slots per node (deg~Poisson(32), max~58)

// R13: fill+gemm1 co-scheduled by BLOCK PARTITION (not thread change).
// Cross-round algebra: fill=73.5us (atomic-latency-bound, VALU 5.7%),
// gemm1=55us (VALU/load-stall-bound) -- complementary pipes, independent
// inputs. R1's fused failure was confounded by the 4-edge int4 fill
// regression; here the champion 1-edge fill is kept BYTE-FOR-BYTE and gemm1
// supers (8 consecutive blocks, preserving blockIdx%8 -> XCD pass mapping)
// are interleaved 1-in-41 so gemm1 blocks dispatch throughout fill's
// lifetime and soak idle VALU slots next to memory-stalled fill waves.
// Fill occupancy is wave-slot-limited (8 blocks/CU) -> unchanged by the
// fused kernel's higher VGPR count.
constexpr int FILL_PASSES = 8;
constexpr int NODES_PER_PASS = 6250;              // 8*6250 = 50000
constexpr int FILL_CHUNKS = 6250;                 // 6250*256 = NE exactly
constexpr int G1_PERIOD = 41;                     // 1 gemm1 super per 41
constexpr int G1_SLOT = 20;
constexpr int G1_VBLOCKS = 1250;                  // 1250*40 = 50000 nodes
constexpr int TOTAL_SUPERS = 6417;                // 157 gemm1 + 6260 fill supers
constexpr int FUSED_BLOCKS = TOTAL_SUPERS * 8;    // 51336

// R12: 16 lanes/node agg form (neutral vs 7-lane but kept; R4 champion).
constexpr int A1_NODES = 16;                       // nodes per agg1g2 block
constexpr int A1_BLOCKS = NN / A1_NODES;           // 3125 (exact)
constexpr int A2_BLOCKS = NN / 16;                 // 3125 (exact)

// workspace layout (bytes)
#define OFF_CNT      0            // int[50000] atomic cursor; == deg after fill
#define OFF_GSUM     200000       // float[128*20]
#define OFF_GCNT     210240       // float[128]
#define ZERO_BYTES   210752
#define OFF_ADJ      210752       // ushort[50000*96] = 9.6MB bucketed adjacency
#define OFF_X1F      9810816      // fp8[50000*128] rows 128B-aligned (6.4MB)
#define OFF_X2B      16210816     // bf16[50000*32] rows 64B (3.2MB)
// end: 19410816 (~19MB)

typedef float v2f __attribute__((ext_vector_type(2)));

// ---- bf16 helpers ---------------------------------------------------------
__device__ __forceinline__ unsigned short f2bf(float x) {      // RNE
    unsigned int v = __float_as_uint(x);
    return (unsigned short)((v + 0x7FFFu + ((v >> 16) & 1u)) >> 16);
}
__device__ __forceinline__ float bflo(unsigned int u) { return __uint_as_float(u << 16); }
__device__ __forceinline__ float bfhi(unsigned int u) { return __uint_as_float(u & 0xFFFF0000u); }

// ---- fused: XCD-aware bucketed fill + interleaved gemm1 supers ------------
__global__ __launch_bounds__(256) void k_fill_gemm1(
        const int* __restrict__ src, const int* __restrict__ dst,
        int* __restrict__ cnt, unsigned short* __restrict__ adj,
        const float4* __restrict__ feat4, const float* __restrict__ W1,
        unsigned int* __restrict__ X1f) {
    const unsigned int super = blockIdx.x >> 3;
    const unsigned int lane8 = blockIdx.x & 7;        // == XCD under round-robin
    const unsigned int qq = super / G1_PERIOD;
    const unsigned int rr = super - qq * G1_PERIOD;

    if (rr != G1_SLOT) {
        // ---- fill path (champion form: 1 edge/thread, pass = blockIdx&7) --
        const int chunk = (int)(super - qq - (rr > G1_SLOT ? 1u : 0u));
        if (chunk >= FILL_CHUNKS) return;
        const int i = chunk * 256 + threadIdx.x;      // < NE exactly
        const int d = dst[i];
        const int lo = (int)lane8 * NODES_PER_PASS;
        if (d >= lo && d < lo + NODES_PER_PASS) {
            const int p = atomicAdd(&cnt[d], 1);
            if (p < BSTRIDE) adj[d * BSTRIDE + p] = (unsigned short)src[i];
        }
        return;
    }

    // ---- gemm1 path: X1f = fp8_e4m3(feat @ W1), 50000x128 @ 128x100 ------
    const int gb = (int)(qq * 8 + lane8);
    if (gb >= G1_VBLOCKS) return;
    const int t = threadIdx.x;
    if (t >= 250) return;
    const int cg = t % 25;            // cols [4cg, 4cg+4)
    const int nq = t / 25;            // node quad within block
    const int node0 = gb * 40 + nq * 4;
    const int col0 = cg * 4;

    float acc[4][4];
#pragma unroll
    for (int i = 0; i < 4; ++i)
#pragma unroll
        for (int j = 0; j < 4; ++j) acc[i][j] = 0.f;

    for (int k4 = 0; k4 < 32; ++k4) {
        float4 f[4];
#pragma unroll
        for (int i = 0; i < 4; ++i) f[i] = feat4[(node0 + i) * 32 + k4];
        float4 wr[4];
#pragma unroll
        for (int kk = 0; kk < 4; ++kk)
            wr[kk] = *(const float4*)(W1 + (k4 * 4 + kk) * 100 + col0);
#pragma unroll
        for (int kk = 0; kk < 4; ++kk) {
#pragma unroll
            for (int i = 0; i < 4; ++i) {
                const float fv = (kk == 0) ? f[i].x
                               : (kk == 1) ? f[i].y
                               : (kk == 2) ? f[i].z : f[i].w;
                acc[i][0] += fv * wr[kk].x;
                acc[i][1] += fv * wr[kk].y;
                acc[i][2] += fv * wr[kk].z;
                acc[i][3] += fv * wr[kk].w;
            }
        }
    }
#pragma unroll
    for (int i = 0; i < 4; ++i) {
        int u = 0;
        u = __builtin_amdgcn_cvt_pk_fp8_f32(acc[i][0], acc[i][1], u, false);
        u = __builtin_amdgcn_cvt_pk_fp8_f32(acc[i][2], acc[i][3], u, true);
        X1f[(node0 + i) * 32 + cg] = (unsigned int)u;
        if (cg == 24) {  // zero pad cols 100..127 (uints 25..31)
#pragma unroll
            for (int z = 25; z < 32; ++z) X1f[(node0 + i) * 32 + z] = 0u;
        }
    }
}

// ---- fused layer-1 aggregate + gemm2, 16 lanes/node ----------------------
// Lane layout per node: l = t&15, q = l&7 (16-col slice, q<7 active),
// half = l>>3 (edge-list half). Each half serially gathers its d/2 edges
// (one 128B row line per edge, split over 7x16B lane loads); halves merge
// via shfl_xor(8). Phase 2: X2b = bf16(h @ W2), exactly 1 slot/thread.
__global__ __launch_bounds__(256) void k_agg1g2(
        const uint4* __restrict__ X1u, const int* __restrict__ cnt,
        const unsigned short* __restrict__ adj, const float* __restrict__ b1,
        const float* __restrict__ W2, unsigned int* __restrict__ X2b) {
    __shared__ float hl[A1_NODES * 100];   // 6.4KB relu'd layer-1 rows
    __shared__ float w2s[100 * 20];        // 8KB
    const int t = threadIdx.x;
    const int node0 = blockIdx.x * A1_NODES;
    for (int i = t; i < 2000; i += 256) w2s[i] = W2[i];

    const int nl   = t >> 4;
    const int l    = t & 15;
    const int q    = l & 7;              // cols [16q,16q+16), active q<7
    const int half = l >> 3;
    const int node = node0 + nl;         // always < NN (3125*16 = 50000)
    const int d = cnt[node];
    const unsigned short* ab = adj + node * BSTRIDE;
    float a[16];
#pragma unroll
    for (int j = 0; j < 16; ++j) a[j] = 0.f;

#define ACC4(UU, B) { v2f l_ = __builtin_amdgcn_cvt_pk_f32_fp8((int)(UU), false); \
                      v2f h_ = __builtin_amdgcn_cvt_pk_f32_fp8((int)(UU), true);  \
                      a[B+0] += l_.x; a[B+1] += l_.y; a[B+2] += h_.x; a[B+3] += h_.y; }
#define SET4(UU, B) { v2f l_ = __builtin_amdgcn_cvt_pk_f32_fp8((int)(UU), false); \
                      v2f h_ = __builtin_amdgcn_cvt_pk_f32_fp8((int)(UU), true);  \
                      a[B+0] = l_.x; a[B+1] = l_.y; a[B+2] = h_.x; a[B+3] = h_.y; }

    if (q < 7) {
        if (d == 0) {
            if (half == 0) {             // keep prior feature; half 1 adds 0
                const uint4 u = X1u[node * 8 + q];
                SET4(u.x, 0) SET4(u.y, 4) SET4(u.z, 8) SET4(u.w, 12)
            }
        } else {
            const int i0 = half ? (d >> 1) : 0;
            const int i1 = half ? d : (d >> 1);
            for (int i = i0; i < i1; ++i) {
                const int s = (int)ab[i];        // broadcast in 8-lane half
                const uint4 u = X1u[s * 8 + q];  // 16B of 128B row
                ACC4(u.x, 0) ACC4(u.y, 4) ACC4(u.z, 8) ACC4(u.w, 12)
            }
        }
    }
#undef ACC4
#undef SET4
    // merge halves (all 256 threads participate; 16-lane groups wave-aligned)
#pragma unroll
    for (int j = 0; j < 16; ++j) a[j] += __shfl_xor(a[j], 8);

    if (half == 0 && q < 7) {
        if (d > 0) {
            const float inv = 1.f / (float)d;
#pragma unroll
            for (int j = 0; j < 16; ++j) a[j] *= inv;
        }
        const int col0 = 16 * q;
        float* hrow = hl + nl * 100 + col0;
        const int nc = (q < 6) ? 16 : 4;       // q==6: cols 96..99 only
#pragma unroll 4
        for (int j = 0; j < nc; ++j)
            hrow[j] = fmaxf(a[j] + b1[col0 + j], 0.f);
    }
    __syncthreads();

    // phase 2: thread = (node, slot); slot<10 -> bf16 pair, else zero pad
    const int j = t & 15;
    unsigned int o = 0u;
    if (j < 10) {
        const float* h = hl + nl * 100;
        float a0 = 0.f, a1 = 0.f;
#pragma unroll 5
        for (int k = 0; k < 100; ++k) {
            const float hv = h[k];
            a0 += hv * w2s[k * 20 + 2 * j];
            a1 += hv * w2s[k * 20 + 2 * j + 1];
        }
        o = (unsigned int)f2bf(a0) | ((unsigned int)f2bf(a1) << 16);
    }
    X2b[node * 16 + j] = o;
}

// ---- layer-2 aggregate + LDS per-graph reduce, 16 lanes/node --------------
__global__ __launch_bounds__(256) void k_agg2(const uint2* __restrict__ X2v,
                                              const int* __restrict__ cnt,
                                              const unsigned short* __restrict__ adj,
                                              const float* __restrict__ b2,
                                              const int* __restrict__ graph_id,
                                              float* __restrict__ g_sum,
                                              float* __restrict__ g_cnt) {
    __shared__ float lsum[NG * 20];
    __shared__ float lcnt[NG];
    const int t = threadIdx.x;
    for (int i = t; i < NG * 20; i += 256) lsum[i] = 0.f;
    if (t < NG) lcnt[t] = 0.f;
    __syncthreads();

    const int nl   = t >> 4;
    const int l    = t & 15;
    const int q    = l & 7;              // cols [4q,4q+4), active q<5
    const int half = l >> 3;
    const int node = blockIdx.x * 16 + nl;   // always < NN (3125*16 = 50000)
    const int d = cnt[node];
    const unsigned short* ab = adj + node * BSTRIDE;
    float ax = 0.f, ay = 0.f, az = 0.f, aw = 0.f;
    if (q < 5) {
        if (d == 0) {
            if (half == 0) {
                const uint2 u = X2v[node * 8 + q];
                ax = bflo(u.x); ay = bfhi(u.x);
                az = bflo(u.y); aw = bfhi(u.y);
            }
        } else {
            const int i0 = half ? (d >> 1) : 0;
            const int i1 = half ? d : (d >> 1);
            for (int i = i0; i < i1; ++i) {
                const int s = (int)ab[i];
                const uint2 u = X2v[s * 8 + q];   // 8B of the 64B bf16 row
                ax += bflo(u.x); ay += bfhi(u.x);
                az += bflo(u.y); aw += bfhi(u.y);
            }
        }
    }
    ax += __shfl_xor(ax, 8);
    ay += __shfl_xor(ay, 8);
    az += __shfl_xor(az, 8);
    aw += __shfl_xor(aw, 8);

    if (half == 0 && q < 5) {
        if (d > 0) {
            const float inv = 1.f / (float)d;
            ax *= inv; ay *= inv; az *= inv; aw *= inv;
        }
        const int col0 = 4 * q;
        const float hx = fmaxf(ax + b2[col0 + 0], 0.f);
        const float hy = fmaxf(ay + b2[col0 + 1], 0.f);
        const float hz = fmaxf(az + b2[col0 + 2], 0.f);
        const float hw = fmaxf(aw + b2[col0 + 3], 0.f);
        const int g = graph_id[node];
        atomicAdd(&lsum[g * 20 + col0 + 0], hx);
        atomicAdd(&lsum[g * 20 + col0 + 1], hy);
        atomicAdd(&lsum[g * 20 + col0 + 2], hz);
        atomicAdd(&lsum[g * 20 + col0 + 3], hw);
    }
    if (l == 0) atomicAdd(&lcnt[graph_id[node]], 1.f);
    __syncthreads();

    const int first = blockIdx.x * 16;
    const int gmin = graph_id[first];
    const int span = graph_id[first + 15] - gmin + 1;
    for (int idx = t; idx < span * 20; idx += 256) {
        const int g = gmin + idx / 20;
        const int c = idx - (idx / 20) * 20;
        const float v = lsum[g * 20 + c];
        if (v != 0.f) atomicAdd(&g_sum[g * 20 + c], v);
    }
    for (int idx = t; idx < span; idx += 256) {
        const float v = lcnt[gmin + idx];
        if (v != 0.f) atomicAdd(&g_cnt[gmin + idx], v);
    }
}

// ---- final: hg = g_sum/max(cnt,1); out = relu([hg,self]@Wf1+bf1)@Wf2+bf2 --
__global__ __launch_bounds__(128) void k_final(const float* __restrict__ g_sum,
                                               const float* __restrict__ g_cnt,
                                               const float* __restrict__ self_feat,
                                               const float* __restrict__ Wf1,
                                               const float* __restrict__ bf1,
                                               const float* __restrict__ Wf2,
                                               const float* __restrict__ bf2,
                                               float* __restrict__ out) {
    const int g = threadIdx.x;  // 128 graphs, one block
    float fused[36];
    const float cnt = fmaxf(g_cnt[g], 1.f);
    const float inv = 1.f / cnt;
#pragma unroll
    for (int j = 0; j < 20; ++j) fused[j] = g_sum[g * 20 + j] * inv;
#pragma unroll
    for (int j = 0; j < 16; ++j) fused[20 + j] = self_feat[g * 16 + j];
    float o = bf2[0];
#pragma unroll
    for (int i = 0; i < 10; ++i) {
        float t = bf1[i];
#pragma unroll
        for (int k = 0; k < 36; ++k) t += fused[k] * Wf1[k * 10 + i];
        o += fmaxf(t, 0.f) * Wf2[i];
    }
    out[g] = o;
}

extern "C" void kernel_launch(void* const* d_in, const int* in_sizes, int n_in,
                              void* d_out, int out_size, void* d_ws, size_t ws_size,
                              hipStream_t stream) {
    const float* feat      = (const float*)d_in[0];
    const float* self_feat = (const float*)d_in[1];
    const int*   src       = (const int*)d_in[2];
    const int*   dst       = (const int*)d_in[3];
    const int*   graph_id  = (const int*)d_in[4];
    const float* W1        = (const float*)d_in[5];
    const float* b1        = (const float*)d_in[6];
    const float* W2        = (const float*)d_in[7];
    const float* b2        = (const float*)d_in[8];
    const float* Wf1       = (const float*)d_in[9];
    const float* bf1       = (const float*)d_in[10];
    const float* Wf2       = (const float*)d_in[11];
    const float* bf2       = (const float*)d_in[12];

    char* w = (char*)d_ws;
    int*            cnt      = (int*)(w + OFF_CNT);
    float*          g_sum    = (float*)(w + OFF_GSUM);
    float*          g_cnt    = (float*)(w + OFF_GCNT);
    unsigned short* adj      = (unsigned short*)(w + OFF_ADJ);
    unsigned int*   X1f      = (unsigned int*)(w + OFF_X1F);
    unsigned int*   X2b      = (unsigned int*)(w + OFF_X2B);

    hipMemsetAsync(w, 0, ZERO_BYTES, stream);  // cnt + g_sum + g_cnt

    k_fill_gemm1<<<FUSED_BLOCKS, 256, 0, stream>>>(src, dst, cnt, adj,
                                                   (const float4*)feat, W1, X1f);
    k_agg1g2<<<A1_BLOCKS, 256, 0, stream>>>((const uint4*)X1f, cnt, adj, b1,
                                            W2, X2b);
    k_agg2<<<A2_BLOCKS, 256, 0, stream>>>((const uint2*)X2b, cnt,
                                          adj, b2, graph_id, g_sum, g_cnt);
    k_final<<<1, 128, 0, stream>>>(g_sum, g_cnt, self_feat, Wf1, bf1, Wf2, bf2,
                                   (float*)d_out);
}

// Round 6
// 260.622 us; speedup vs baseline: 1.4008x; 1.0376x over previous
//
#include <hip/hip_runtime.h>

constexpr int NN = 50000;    // nodes
constexpr int NE = 1600000;  // edges
constexpr int NG = 128;      // graphs
constexpr int BSTRIDE = 96;  // adj bucket slots per node (deg~Poisson(32), max~58)

// R13 (kept): fill+gemm1 co-scheduled by block partition; champion 1-edge
// fill byte-for-byte + gemm1 supers 1-in-41 preserving blockIdx%8 XCD map.
// Measured R5: 107us steady vs 128.5 serial.
constexpr int FILL_PASSES = 8;
constexpr int NODES_PER_PASS = 6250;              // 8*6250 = 50000
constexpr int FILL_CHUNKS = 6250;                 // 6250*256 = NE exactly
constexpr int G1_PERIOD = 41;                     // 1 gemm1 super per 41
constexpr int G1_SLOT = 20;
constexpr int G1_VBLOCKS = 1250;                  // 1250*40 = 50000 nodes
constexpr int TOTAL_SUPERS = 6417;                // 157 gemm1 + 6260 fill supers
constexpr int FUSED_BLOCKS = TOTAL_SUPERS * 8;    // 51336

// R14: aggs are MLP-bound (R12 half-split neutral because both halves share
// one wave -> still 1 outstanding gather/wave; 32 waves/CU x 1 x ~800cy for
// 6250 edges/CU = ~65us = observed). Fix: 4-deep explicit gather pipeline --
// ushort4 adj read + 4 independent row gathers in flight before accumulate.
// Range split at multiple-of-4 keeps the 8B adj loads aligned.
constexpr int A1_NODES = 16;                       // nodes per agg1g2 block
constexpr int A1_BLOCKS = NN / A1_NODES;           // 3125 (exact)
constexpr int A2_BLOCKS = NN / 16;                 // 3125 (exact)

// workspace layout (bytes)
#define OFF_CNT      0            // int[50000] atomic cursor; == deg after fill
#define OFF_GSUM     200000       // float[128*20]
#define OFF_GCNT     210240       // float[128]
#define ZERO_BYTES   210752
#define OFF_ADJ      210752       // ushort[50000*96] = 9.6MB bucketed adjacency
#define OFF_X1F      9810816      // fp8[50000*128] rows 128B-aligned (6.4MB)
#define OFF_X2B      16210816     // bf16[50000*32] rows 64B (3.2MB)
// end: 19410816 (~19MB)

typedef float v2f __attribute__((ext_vector_type(2)));

// ---- bf16 helpers ---------------------------------------------------------
__device__ __forceinline__ unsigned short f2bf(float x) {      // RNE
    unsigned int v = __float_as_uint(x);
    return (unsigned short)((v + 0x7FFFu + ((v >> 16) & 1u)) >> 16);
}
__device__ __forceinline__ float bflo(unsigned int u) { return __uint_as_float(u << 16); }
__device__ __forceinline__ float bfhi(unsigned int u) { return __uint_as_float(u & 0xFFFF0000u); }

// ---- fused: XCD-aware bucketed fill + interleaved gemm1 supers ------------
__global__ __launch_bounds__(256) void k_fill_gemm1(
        const int* __restrict__ src, const int* __restrict__ dst,
        int* __restrict__ cnt, unsigned short* __restrict__ adj,
        const float4* __restrict__ feat4, const float* __restrict__ W1,
        unsigned int* __restrict__ X1f) {
    const unsigned int super = blockIdx.x >> 3;
    const unsigned int lane8 = blockIdx.x & 7;        // == XCD under round-robin
    const unsigned int qq = super / G1_PERIOD;
    const unsigned int rr = super - qq * G1_PERIOD;

    if (rr != G1_SLOT) {
        // ---- fill path (champion form: 1 edge/thread, pass = blockIdx&7) --
        const int chunk = (int)(super - qq - (rr > G1_SLOT ? 1u : 0u));
        if (chunk >= FILL_CHUNKS) return;
        const int i = chunk * 256 + threadIdx.x;      // < NE exactly
        const int d = dst[i];
        const int lo = (int)lane8 * NODES_PER_PASS;
        if (d >= lo && d < lo + NODES_PER_PASS) {
            const int p = atomicAdd(&cnt[d], 1);
            if (p < BSTRIDE) adj[d * BSTRIDE + p] = (unsigned short)src[i];
        }
        return;
    }

    // ---- gemm1 path: X1f = fp8_e4m3(feat @ W1), 50000x128 @ 128x100 ------
    const int gb = (int)(qq * 8 + lane8);
    if (gb >= G1_VBLOCKS) return;
    const int t = threadIdx.x;
    if (t >= 250) return;
    const int cg = t % 25;            // cols [4cg, 4cg+4)
    const int nq = t / 25;            // node quad within block
    const int node0 = gb * 40 + nq * 4;
    const int col0 = cg * 4;

    float acc[4][4];
#pragma unroll
    for (int i = 0; i < 4; ++i)
#pragma unroll
        for (int j = 0; j < 4; ++j) acc[i][j] = 0.f;

    for (int k4 = 0; k4 < 32; ++k4) {
        float4 f[4];
#pragma unroll
        for (int i = 0; i < 4; ++i) f[i] = feat4[(node0 + i) * 32 + k4];
        float4 wr[4];
#pragma unroll
        for (int kk = 0; kk < 4; ++kk)
            wr[kk] = *(const float4*)(W1 + (k4 * 4 + kk) * 100 + col0);
#pragma unroll
        for (int kk = 0; kk < 4; ++kk) {
#pragma unroll
            for (int i = 0; i < 4; ++i) {
                const float fv = (kk == 0) ? f[i].x
                               : (kk == 1) ? f[i].y
                               : (kk == 2) ? f[i].z : f[i].w;
                acc[i][0] += fv * wr[kk].x;
                acc[i][1] += fv * wr[kk].y;
                acc[i][2] += fv * wr[kk].z;
                acc[i][3] += fv * wr[kk].w;
            }
        }
    }
#pragma unroll
    for (int i = 0; i < 4; ++i) {
        int u = 0;
        u = __builtin_amdgcn_cvt_pk_fp8_f32(acc[i][0], acc[i][1], u, false);
        u = __builtin_amdgcn_cvt_pk_fp8_f32(acc[i][2], acc[i][3], u, true);
        X1f[(node0 + i) * 32 + cg] = (unsigned int)u;
        if (cg == 24) {  // zero pad cols 100..127 (uints 25..31)
#pragma unroll
            for (int z = 25; z < 32; ++z) X1f[(node0 + i) * 32 + z] = 0u;
        }
    }
}

// ---- fused layer-1 aggregate + gemm2, 16 lanes/node, 4-deep gather --------
// Lane layout per node: l = t&15, q = l&7 (16-col slice, q<7 active),
// half = l>>3. Half0 owns [0,m), half1 [m,d), m = (d>>1)&~3 so both ranges
// start at a multiple of 4 (aligned ushort4 adj reads). Main loop keeps 4
// row-gathers in flight per half before accumulating (MLP 1 -> 4).
__global__ __launch_bounds__(256) void k_agg1g2(
        const uint4* __restrict__ X1u, const int* __restrict__ cnt,
        const unsigned short* __restrict__ adj, const float* __restrict__ b1,
        const float* __restrict__ W2, unsigned int* __restrict__ X2b) {
    __shared__ float hl[A1_NODES * 100];   // 6.4KB relu'd layer-1 rows
    __shared__ float w2s[100 * 20];        // 8KB
    const int t = threadIdx.x;
    const int node0 = blockIdx.x * A1_NODES;
    for (int i = t; i < 2000; i += 256) w2s[i] = W2[i];

    const int nl   = t >> 4;
    const int l    = t & 15;
    const int q    = l & 7;              // cols [16q,16q+16), active q<7
    const int half = l >> 3;
    const int node = node0 + nl;         // always < NN (3125*16 = 50000)
    const int d = cnt[node];
    const unsigned short* ab = adj + node * BSTRIDE;
    float a[16];
#pragma unroll
    for (int j = 0; j < 16; ++j) a[j] = 0.f;

#define ACC4(UU, B) { v2f l_ = __builtin_amdgcn_cvt_pk_f32_fp8((int)(UU), false); \
                      v2f h_ = __builtin_amdgcn_cvt_pk_f32_fp8((int)(UU), true);  \
                      a[B+0] += l_.x; a[B+1] += l_.y; a[B+2] += h_.x; a[B+3] += h_.y; }
#define SET4(UU, B) { v2f l_ = __builtin_amdgcn_cvt_pk_f32_fp8((int)(UU), false); \
                      v2f h_ = __builtin_amdgcn_cvt_pk_f32_fp8((int)(UU), true);  \
                      a[B+0] = l_.x; a[B+1] = l_.y; a[B+2] = h_.x; a[B+3] = h_.y; }
#define ACCU4(U) ACC4((U).x, 0) ACC4((U).y, 4) ACC4((U).z, 8) ACC4((U).w, 12)

    if (q < 7) {
        if (d == 0) {
            if (half == 0) {             // keep prior feature; half 1 adds 0
                const uint4 u = X1u[node * 8 + q];
                SET4(u.x, 0) SET4(u.y, 4) SET4(u.z, 8) SET4(u.w, 12)
            }
        } else {
            const int m  = (d >> 1) & ~3;        // 4-aligned split point
            const int i0 = half ? m : 0;
            const int i1 = half ? d : m;
            int i = i0;
            for (; i + 4 <= i1; i += 4) {
                const ushort4 s4 = *(const ushort4*)(ab + i);  // 8B, aligned
                const uint4 u0 = X1u[(int)s4.x * 8 + q];       // 4 gathers
                const uint4 u1 = X1u[(int)s4.y * 8 + q];       // in flight
                const uint4 u2 = X1u[(int)s4.z * 8 + q];
                const uint4 u3 = X1u[(int)s4.w * 8 + q];
                ACCU4(u0) ACCU4(u1) ACCU4(u2) ACCU4(u3)
            }
            for (; i < i1; ++i) {                               // tail <4
                const uint4 u = X1u[(int)ab[i] * 8 + q];
                ACCU4(u)
            }
        }
    }
#undef ACCU4
#undef ACC4
#undef SET4
    // merge halves (all 256 threads participate; 16-lane groups wave-aligned)
#pragma unroll
    for (int j = 0; j < 16; ++j) a[j] += __shfl_xor(a[j], 8);

    if (half == 0 && q < 7) {
        if (d > 0) {
            const float inv = 1.f / (float)d;
#pragma unroll
            for (int j = 0; j < 16; ++j) a[j] *= inv;
        }
        const int col0 = 16 * q;
        float* hrow = hl + nl * 100 + col0;
        const int nc = (q < 6) ? 16 : 4;       // q==6: cols 96..99 only
#pragma unroll 4
        for (int j = 0; j < nc; ++j)
            hrow[j] = fmaxf(a[j] + b1[col0 + j], 0.f);
    }
    __syncthreads();

    // phase 2: thread = (node, slot); slot<10 -> bf16 pair, else zero pad
    const int j = t & 15;
    unsigned int o = 0u;
    if (j < 10) {
        const float* h = hl + nl * 100;
        float a0 = 0.f, a1 = 0.f;
#pragma unroll 5
        for (int k = 0; k < 100; ++k) {
            const float hv = h[k];
            a0 += hv * w2s[k * 20 + 2 * j];
            a1 += hv * w2s[k * 20 + 2 * j + 1];
        }
        o = (unsigned int)f2bf(a0) | ((unsigned int)f2bf(a1) << 16);
    }
    X2b[node * 16 + j] = o;
}

// ---- layer-2 aggregate + LDS per-graph reduce, 4-deep gather --------------
__global__ __launch_bounds__(256) void k_agg2(const uint2* __restrict__ X2v,
                                              const int* __restrict__ cnt,
                                              const unsigned short* __restrict__ adj,
                                              const float* __restrict__ b2,
                                              const int* __restrict__ graph_id,
                                              float* __restrict__ g_sum,
                                              float* __restrict__ g_cnt) {
    __shared__ float lsum[NG * 20];
    __shared__ float lcnt[NG];
    const int t = threadIdx.x;
    for (int i = t; i < NG * 20; i += 256) lsum[i] = 0.f;
    if (t < NG) lcnt[t] = 0.f;
    __syncthreads();

    const int nl   = t >> 4;
    const int l    = t & 15;
    const int q    = l & 7;              // cols [4q,4q+4), active q<5
    const int half = l >> 3;
    const int node = blockIdx.x * 16 + nl;   // always < NN (3125*16 = 50000)
    const int d = cnt[node];
    const unsigned short* ab = adj + node * BSTRIDE;
    float ax = 0.f, ay = 0.f, az = 0.f, aw = 0.f;
#define ACCU2(U) { ax += bflo((U).x); ay += bfhi((U).x); \
                   az += bflo((U).y); aw += bfhi((U).y); }
    if (q < 5) {
        if (d == 0) {
            if (half == 0) {
                const uint2 u = X2v[node * 8 + q];
                ax = bflo(u.x); ay = bfhi(u.x);
                az = bflo(u.y); aw = bfhi(u.y);
            }
        } else {
            const int m  = (d >> 1) & ~3;        // 4-aligned split point
            const int i0 = half ? m : 0;
            const int i1 = half ? d : m;
            int i = i0;
            for (; i + 4 <= i1; i += 4) {
                const ushort4 s4 = *(const ushort4*)(ab + i);  // 8B, aligned
                const uint2 u0 = X2v[(int)s4.x * 8 + q];       // 4 gathers
                const uint2 u1 = X2v[(int)s4.y * 8 + q];       // in flight
                const uint2 u2 = X2v[(int)s4.z * 8 + q];
                const uint2 u3 = X2v[(int)s4.w * 8 + q];
                ACCU2(u0) ACCU2(u1) ACCU2(u2) ACCU2(u3)
            }
            for (; i < i1; ++i) {                               // tail <4
                const uint2 u = X2v[(int)ab[i] * 8 + q];
                ACCU2(u)
            }
        }
    }
#undef ACCU2
    ax += __shfl_xor(ax, 8);
    ay += __shfl_xor(ay, 8);
    az += __shfl_xor(az, 8);
    aw += __shfl_xor(aw, 8);

    if (half == 0 && q < 5) {
        if (d > 0) {
            const float inv = 1.f / (float)d;
            ax *= inv; ay *= inv; az *= inv; aw *= inv;
        }
        const int col0 = 4 * q;
        const float hx = fmaxf(ax + b2[col0 + 0], 0.f);
        const float hy = fmaxf(ay + b2[col0 + 1], 0.f);
        const float hz = fmaxf(az + b2[col0 + 2], 0.f);
        const float hw = fmaxf(aw + b2[col0 + 3], 0.f);
        const int g = graph_id[node];
        atomicAdd(&lsum[g * 20 + col0 + 0], hx);
        atomicAdd(&lsum[g * 20 + col0 + 1], hy);
        atomicAdd(&lsum[g * 20 + col0 + 2], hz);
        atomicAdd(&lsum[g * 20 + col0 + 3], hw);
    }
    if (l == 0) atomicAdd(&lcnt[graph_id[node]], 1.f);
    __syncthreads();

    const int first = blockIdx.x * 16;
    const int gmin = graph_id[first];
    const int span = graph_id[first + 15] - gmin + 1;
    for (int idx = t; idx < span * 20; idx += 256) {
        const int g = gmin + idx / 20;
        const int c = idx - (idx / 20) * 20;
        const float v = lsum[g * 20 + c];
        if (v != 0.f) atomicAdd(&g_sum[g * 20 + c], v);
    }
    for (int idx = t; idx < span; idx += 256) {
        const float v = lcnt[gmin + idx];
        if (v != 0.f) atomicAdd(&g_cnt[gmin + idx], v);
    }
}

// ---- final: hg = g_sum/max(cnt,1); out = relu([hg,self]@Wf1+bf1)@Wf2+bf2 --
__global__ __launch_bounds__(128) void k_final(const float* __restrict__ g_sum,
                                               const float* __restrict__ g_cnt,
                                               const float* __restrict__ self_feat,
                                               const float* __restrict__ Wf1,
                                               const float* __restrict__ bf1,
                                               const float* __restrict__ Wf2,
                                               const float* __restrict__ bf2,
                                               float* __restrict__ out) {
    const int g = threadIdx.x;  // 128 graphs, one block
    float fused[36];
    const float cnt = fmaxf(g_cnt[g], 1.f);
    const float inv = 1.f / cnt;
#pragma unroll
    for (int j = 0; j < 20; ++j) fused[j] = g_sum[g * 20 + j] * inv;
#pragma unroll
    for (int j = 0; j < 16; ++j) fused[20 + j] = self_feat[g * 16 + j];
    float o = bf2[0];
#pragma unroll
    for (int i = 0; i < 10; ++i) {
        float t = bf1[i];
#pragma unroll
        for (int k = 0; k < 36; ++k) t += fused[k] * Wf1[k * 10 + i];
        o += fmaxf(t, 0.f) * Wf2[i];
    }
    out[g] = o;
}

extern "C" void kernel_launch(void* const* d_in, const int* in_sizes, int n_in,
                              void* d_out, int out_size, void* d_ws, size_t ws_size,
                              hipStream_t stream) {
    const float* feat      = (const float*)d_in[0];
    const float* self_feat = (const float*)d_in[1];
    const int*   src       = (const int*)d_in[2];
    const int*   dst       = (const int*)d_in[3];
    const int*   graph_id  = (const int*)d_in[4];
    const float* W1        = (const float*)d_in[5];
    const float* b1        = (const float*)d_in[6];
    const float* W2        = (const float*)d_in[7];
    const float* b2        = (const float*)d_in[8];
    const float* Wf1       = (const float*)d_in[9];
    const float* bf1       = (const float*)d_in[10];
    const float* Wf2       = (const float*)d_in[11];
    const float* bf2       = (const float*)d_in[12];

    char* w = (char*)d_ws;
    int*            cnt      = (int*)(w + OFF_CNT);
    float*          g_sum    = (float*)(w + OFF_GSUM);
    float*          g_cnt    = (float*)(w + OFF_GCNT);
    unsigned short* adj      = (unsigned short*)(w + OFF_ADJ);
    unsigned int*   X1f      = (unsigned int*)(w + OFF_X1F);
    unsigned int*   X2b      = (unsigned int*)(w + OFF_X2B);

    hipMemsetAsync(w, 0, ZERO_BYTES, stream);  // cnt + g_sum + g_cnt

    k_fill_gemm1<<<FUSED_BLOCKS, 256, 0, stream>>>(src, dst, cnt, adj,
                                                   (const float4*)feat, W1, X1f);
    k_agg1g2<<<A1_BLOCKS, 256, 0, stream>>>((const uint4*)X1f, cnt, adj, b1,
                                            W2, X2b);
    k_agg2<<<A2_BLOCKS, 256, 0, stream>>>((const uint2*)X2b, cnt,
                                          adj, b2, graph_id, g_sum, g_cnt);
    k_final<<<1, 128, 0, stream>>>(g_sum, g_cnt, self_feat, Wf1, bf1, Wf2, bf2,
                                   (float*)d_out);
}